// Round 5
// baseline (21459.373 us; speedup 1.0000x reference)
//
#include <hip/hip_runtime.h>
#include <cmath>
#include <cstdint>

typedef __bf16 bf16;
typedef __bf16 bf16x8 __attribute__((ext_vector_type(8)));
typedef float f32x4 __attribute__((ext_vector_type(4)));

#define NWG 128

static __device__ __forceinline__ float gelu_exact(float x) {
    return 0.5f * x * (1.f + erff(x * 0.70710678118654752f));
}

// ---------- fp32 -> bf16 convert of x with SAME padding rows (t=-1 and t=2000 zeroed) ----------
__global__ void cvt_xpad_kernel(const float* __restrict__ x, bf16* __restrict__ xp) {
    int idx = blockIdx.x * 256 + threadIdx.x;
    if (idx >= 8 * 2002 * 128) return;
    int c = idx & 127;
    int rest = idx >> 7;
    int tp = rest % 2002;
    int b = rest / 2002;
    float v = 0.f;
    if (tp >= 1 && tp <= 2000) v = x[(b * 2000 + tp - 1) * 128 + c];
    xp[idx] = (bf16)v;
}

// ---------- generic transpose+convert: in fp32 [R][C] -> out [C][Rpad], zero pad r in [R,Rpad) ----------
template <typename OT>
__global__ void transpose_cvt_kernel(const float* __restrict__ in, OT* __restrict__ out,
                                     int R, int C, int Rpad) {
    __shared__ float tile[32][33];
    int tx = threadIdx.x & 31, ty = threadIdx.x >> 5;
    int r0 = blockIdx.y * 32, c0 = blockIdx.x * 32;
    for (int i = ty; i < 32; i += 8) {
        int r = r0 + i, c = c0 + tx;
        tile[i][tx] = (r < R && c < C) ? in[(size_t)r * C + c] : 0.f;
    }
    __syncthreads();
    for (int i = ty; i < 32; i += 8) {
        int c = c0 + i, r = r0 + tx;
        if (c < C && r < Rpad) out[(size_t)c * Rpad + r] = (OT)tile[tx][i];
    }
}

// ---------- zero h1 pad row (t=2000 per batch) + hbuf[2][4096] + flags/counter ----------
__global__ void zero_aux_kernel(bf16* __restrict__ h1, float* __restrict__ hz) {
    int idx = blockIdx.x * 256 + threadIdx.x;
    if (idx < 8 * 4096) {
        int b = idx >> 12, n = idx & 4095;
        h1[((size_t)(b * 2001 + 2000)) * 4096 + n] = (bf16)0.f;
    }
    int j = idx - 8 * 4096;
    if (j >= 0 && j < 8448) hz[j] = 0.f;
}

// ---------- unified bf16 MFMA GEMM, 128x128 tile, BK=32, global_load_lds staging ----------
template <int MODE>
__launch_bounds__(256)
__global__ void gemm_kernel(const bf16* __restrict__ A, const bf16* __restrict__ BT,
                            const float* __restrict__ bias, void* __restrict__ Cout) {
    constexpr int KTOT = (MODE == 0) ? 384 : (MODE == 1) ? 12288 : 1024;
    constexpr int MTOT = (MODE == 0) ? 16000 : (MODE == 1) ? 8000 : 8192;
    __shared__ __align__(16) bf16 As[128 * 32];
    __shared__ __align__(16) bf16 Bs[128 * 32];
    const int tid = threadIdx.x;
    const int lane = tid & 63, wave = tid >> 6;
    const int m0 = blockIdx.y * 128, n0 = blockIdx.x * 128;
    const int wm = (wave >> 1) * 64, wn = (wave & 1) * 64;

    f32x4 acc[4][4];
#pragma unroll
    for (int mi = 0; mi < 4; ++mi)
#pragma unroll
        for (int ni = 0; ni < 4; ++ni) acc[mi][ni] = (f32x4){0.f, 0.f, 0.f, 0.f};

    for (int kt = 0; kt < KTOT / 32; ++kt) {
        const int k0 = kt * 32;
        __syncthreads();
#pragma unroll
        for (int s = 0; s < 2; ++s) {
            const int ch = s * 256 + tid;
            const int row = ch >> 2;
            const int ko = (ch & 3) * 8;
            int m = m0 + row;
            if (m > MTOT - 1) m = MTOT - 1;
            const bf16* ga;
            if (MODE == 0) {
                int b = m / 2000, t = m - b * 2000;
                ga = A + ((size_t)(b * 2002 + t + (k0 >> 7)) * 128 + (k0 & 127) + ko);
            } else if (MODE == 1) {
                int b = m / 1000, t = m - b * 1000;
                ga = A + ((size_t)(b * 2001 + 2 * t + (k0 >> 12)) * 4096 + (k0 & 4095) + ko);
            } else {
                ga = A + ((size_t)m * 1024 + k0 + ko);
            }
            const bf16* gb = BT + ((size_t)(n0 + row) * KTOT + k0 + ko);
            const int chbase = s * 256 + wave * 64;
            __builtin_amdgcn_global_load_lds(
                (const __attribute__((address_space(1))) uint32_t*)ga,
                (__attribute__((address_space(3))) uint32_t*)&As[chbase * 8], 16, 0, 0);
            __builtin_amdgcn_global_load_lds(
                (const __attribute__((address_space(1))) uint32_t*)gb,
                (__attribute__((address_space(3))) uint32_t*)&Bs[chbase * 8], 16, 0, 0);
        }
        __syncthreads();
        bf16x8 af[4], bfr[4];
#pragma unroll
        for (int i = 0; i < 4; ++i)
            af[i] = *(const bf16x8*)&As[(wm + i * 16 + (lane & 15)) * 32 + (lane >> 4) * 8];
#pragma unroll
        for (int i = 0; i < 4; ++i)
            bfr[i] = *(const bf16x8*)&Bs[(wn + i * 16 + (lane & 15)) * 32 + (lane >> 4) * 8];
#pragma unroll
        for (int mi = 0; mi < 4; ++mi)
#pragma unroll
            for (int ni = 0; ni < 4; ++ni)
                acc[mi][ni] = __builtin_amdgcn_mfma_f32_16x16x32_bf16(af[mi], bfr[ni], acc[mi][ni], 0, 0, 0);
    }

#pragma unroll
    for (int mi = 0; mi < 4; ++mi) {
        int rb = m0 + wm + mi * 16 + (lane >> 4) * 4;
#pragma unroll
        for (int ni = 0; ni < 4; ++ni) {
            int col = n0 + wn + ni * 16 + (lane & 15);
#pragma unroll
            for (int i = 0; i < 4; ++i) {
                int row = rb + i;
                float v = acc[mi][ni][i];
                if (MODE == 0) {
                    float y = gelu_exact(v + bias[col]);
                    int b = row / 2000, t = row - b * 2000;
                    ((bf16*)Cout)[(size_t)(b * 2001 + t) * 4096 + col] = (bf16)y;
                } else if (MODE == 1) {
                    if (row < 8000) {
                        float y = gelu_exact(v + bias[col]);
                        int b = row / 1000, t = row - b * 1000;
                        ((bf16*)Cout)[(size_t)(b * 1024 + col) * 1024 + t] = (bf16)y;
                    }
                } else {
                    ((float*)Cout)[(size_t)row * 2048 + col] = v + bias[col];
                }
            }
        }
    }
}

// ---------- L2-bypassing (LLC-coherent) accessors: sc0 sc1 on gfx950 ----------
static __device__ __forceinline__ void store_llc_f32(float* p, float v) {
    asm volatile("global_store_dword %0, %1, off sc0 sc1" :: "v"(p), "v"(v) : "memory");
}
static __device__ __forceinline__ void store_llc_i32(int* p, int v) {
    asm volatile("global_store_dword %0, %1, off sc0 sc1" :: "v"(p), "v"(v) : "memory");
}
static __device__ __forceinline__ int load_llc_i32(const int* p) {
    int v;
    asm volatile("global_load_dword %0, %1, off sc0 sc1\n\ts_waitcnt vmcnt(0)"
                 : "=&v"(v) : "v"(p) : "memory");
    return v;
}

// ---------- persistent LSTM: 128 WGs, weights in registers, central-counter barrier ----------
__launch_bounds__(256, 1)
__global__ void lstm_persistent_kernel(const float* __restrict__ Zin,
                                       const float* __restrict__ WrT,
                                       float* __restrict__ hbuf,
                                       int* __restrict__ sync,   // sync[0]=arrival ctr, sync[4]=generation
                                       float* __restrict__ out) {
    __shared__ __align__(16) float hs[4096];
    const int tid = threadIdx.x, lane = tid & 63, wave = tid >> 6;
    const int j = blockIdx.x * 4 + wave;               // hidden unit 0..511
    float4 w[2][4];
#pragma unroll
    for (int it = 0; it < 2; ++it) {
        const int k = it * 256 + (lane << 2);
#pragma unroll
        for (int g = 0; g < 4; ++g)
            w[it][g] = *(const float4*)&WrT[(size_t)(g * 512 + j) * 512 + k];
    }
    const int b_lane = ((lane & 1) << 2) | (lane & 2) | ((lane >> 2) & 1);
    const float expo = (float)(2 * (j >> 1)) * (1.f / 512.f);
    const float rate = powf(10000.f, -expo);
    float creg = 0.f;

    // prefetch Zin gates for t=0 (normal cached loads)
    const float* zpt = Zin + ((size_t)(b_lane * 1024)) * 2048;
    float z0 = zpt[j], z1 = zpt[512 + j], z2 = zpt[1024 + j], z3 = zpt[1536 + j];

    for (int t = 0; t < 1024; ++t) {
        const float* hin = hbuf + ((t & 1) << 12);
        float* hout = hbuf + (((t + 1) & 1) << 12);

        // stage h_t into LDS via LLC-coherent loads (bypass L1/L2), all 4 in flight
        {
            const char* pA = (const char*)hin + (tid << 4) + 4096;
            const char* pB = pA + 8192;
            float4 h0, h1v, h2v, h3v;
            asm volatile(
                "global_load_dwordx4 %0, %4, off offset:-4096 sc0 sc1\n\t"
                "global_load_dwordx4 %1, %4, off sc0 sc1\n\t"
                "global_load_dwordx4 %2, %5, off offset:-4096 sc0 sc1\n\t"
                "global_load_dwordx4 %3, %5, off sc0 sc1\n\t"
                "s_waitcnt vmcnt(0)"
                : "=&v"(h0), "=&v"(h1v), "=&v"(h2v), "=&v"(h3v)
                : "v"(pA), "v"(pB)
                : "memory");
            *(float4*)&hs[(tid << 2)] = h0;
            *(float4*)&hs[(tid << 2) + 1024] = h1v;
            *(float4*)&hs[(tid << 2) + 2048] = h2v;
            *(float4*)&hs[(tid << 2) + 3072] = h3v;
        }
        __syncthreads();

        float acc[32];
#pragma unroll
        for (int i = 0; i < 32; ++i) acc[i] = 0.f;
#pragma unroll
        for (int it = 0; it < 2; ++it) {
            const int k = it * 256 + (lane << 2);
#pragma unroll
            for (int b = 0; b < 8; ++b) {
                const float4 h4 = *(const float4*)&hs[b * 512 + k];
#pragma unroll
                for (int g = 0; g < 4; ++g) {
                    acc[b * 4 + g] += h4.x * w[it][g].x;
                    acc[b * 4 + g] += h4.y * w[it][g].y;
                    acc[b * 4 + g] += h4.z * w[it][g].z;
                    acc[b * 4 + g] += h4.w * w[it][g].w;
                }
            }
        }
        // exchange-and-specialize butterfly: 32 sums across 64 lanes
#pragma unroll
        for (int s = 0; s < 5; ++s) {
            const int cnt = 16 >> s;
            const bool up = (lane >> s) & 1;
#pragma unroll
            for (int i = 0; i < 16; ++i) {
                if (i < cnt) {
                    float keep = up ? acc[i + cnt] : acc[i];
                    float send = up ? acc[i] : acc[i + cnt];
                    acc[i] = keep + __shfl_xor(send, 1 << s, 64);
                }
            }
        }
        acc[0] += __shfl_xor(acc[0], 32, 64);
        const float zf_o = __shfl(acc[0], lane + 16, 64);
        const float zg_o = __shfl(acc[0], lane + 8, 64);
        const float zo_o = __shfl(acc[0], lane + 24, 64);
        if (lane < 8) {
            const float zi = acc[0] + z0;
            const float zf = zf_o + z1;
            const float zg = zg_o + z2;
            const float zo = zo_o + z3;
            const float ig = 1.f / (1.f + expf(-zi));
            const float fg = 1.f / (1.f + expf(-zf));
            const float og = 1.f / (1.f + expf(-zo));
            creg = fg * creg + ig * tanhf(zg);
            const float h = og * tanhf(creg);
            store_llc_f32(&hout[b_lane * 512 + j], h);   // write-through to LLC
            const float ang = (float)t * rate;
            const float pe = (j & 1) ? cosf(ang) : sinf(ang);
            out[((size_t)(b_lane * 1024 + t) << 9) + j] = h + pe;  // normal cached store
        }
        // drain this wave's h-stores to the coherence point; syncthreads => all waves drained
        asm volatile("s_waitcnt vmcnt(0)" ::: "memory");
        __syncthreads();

        // prefetch Zin gates for t+1 (independent of barrier; latency hides under wait)
        if (t + 1 < 1024) {
            const float* zp = Zin + ((size_t)(b_lane * 1024 + t + 1)) * 2048;
            z0 = zp[j]; z1 = zp[512 + j]; z2 = zp[1024 + j]; z3 = zp[1536 + j];
        }

        // central-counter barrier: 1 atomic + 1 poller per WG, single generation word
        if (tid == 0) {
            const int target = NWG * (t + 1);
            int old = atomicAdd(sync, 1);           // device-scope, relaxed (no fence)
            if (old == target - 1) {
                store_llc_i32(sync + 4, t + 1);     // last arriver publishes generation
            } else {
                while (load_llc_i32(sync + 4) < t + 1) {}
            }
        }
        __syncthreads();
    }
}

extern "C" void kernel_launch(void* const* d_in, const int* in_sizes, int n_in,
                              void* d_out, int out_size, void* d_ws, size_t ws_size,
                              hipStream_t stream) {
    const float* x  = (const float*)d_in[0];
    const float* w1 = (const float*)d_in[1];
    const float* b1 = (const float*)d_in[2];
    const float* w2 = (const float*)d_in[3];
    const float* b2 = (const float*)d_in[4];
    const float* wk = (const float*)d_in[5];
    const float* wr = (const float*)d_in[6];
    const float* lb = (const float*)d_in[7];
    float* out = (float*)d_out;

    uint8_t* ws = (uint8_t*)d_ws;
    size_t off = 0;
    auto alloc = [&](size_t bytes) {
        void* p = ws + off;
        off += (bytes + 255) & ~(size_t)255;
        return p;
    };
    bf16* xpad = (bf16*)alloc((size_t)8 * 2002 * 128 * 2);
    bf16* W1T  = (bf16*)alloc((size_t)4096 * 384 * 2);
    bf16* W2T  = (bf16*)alloc((size_t)1024 * 12288 * 2);
    bf16* WkT  = (bf16*)alloc((size_t)2048 * 1024 * 2);
    float* WrT = (float*)alloc((size_t)2048 * 512 * 4);
    bf16* h1   = (bf16*)alloc((size_t)8 * 2001 * 4096 * 2);   // Zin aliases this after conv2
    bf16* h2T  = (bf16*)alloc((size_t)8 * 1024 * 1024 * 2);
    float* hz  = (float*)alloc((size_t)8448 * 4);             // hbuf[2][4096] + sync words
    float* Zin = (float*)h1;
    float* hbuf = hz;
    int* sync = (int*)(hz + 8192);

    cvt_xpad_kernel<<<(8 * 2002 * 128 + 255) / 256, 256, 0, stream>>>(x, xpad);
    transpose_cvt_kernel<bf16><<<dim3(128, 12), 256, 0, stream>>>(w1, W1T, 384, 4096, 384);
    transpose_cvt_kernel<bf16><<<dim3(32, 384), 256, 0, stream>>>(w2, W2T, 12288, 1024, 12288);
    transpose_cvt_kernel<bf16><<<dim3(64, 32), 256, 0, stream>>>(wk, WkT, 1000, 2048, 1024);
    transpose_cvt_kernel<float><<<dim3(64, 16), 256, 0, stream>>>(wr, WrT, 512, 2048, 512);
    zero_aux_kernel<<<(8 * 4096 + 8448 + 255) / 256, 256, 0, stream>>>(h1, hz);

    gemm_kernel<0><<<dim3(32, 125), 256, 0, stream>>>(xpad, W1T, b1, (void*)h1);
    gemm_kernel<1><<<dim3(8, 63), 256, 0, stream>>>(h1, W2T, b2, (void*)h2T);
    gemm_kernel<2><<<dim3(16, 64), 256, 0, stream>>>(h2T, WkT, lb, (void*)Zin);

    lstm_persistent_kernel<<<NWG, 256, 0, stream>>>(Zin, WrT, hbuf, sync, out);
}

// Round 6
// 18758.238 us; speedup vs baseline: 1.1440x; 1.1440x over previous
//
#include <hip/hip_runtime.h>
#include <cmath>
#include <cstdint>

typedef __bf16 bf16;
typedef __bf16 bf16x8 __attribute__((ext_vector_type(8)));
typedef float f32x4 __attribute__((ext_vector_type(4)));

#define NWG 128
#define SENT 2.0f   // |h| < 1 strictly => 2.0f is unreachable as real data

static __device__ __forceinline__ float gelu_exact(float x) {
    return 0.5f * x * (1.f + erff(x * 0.70710678118654752f));
}

// ---------- fp32 -> bf16 convert of x with SAME padding rows (t=-1 and t=2000 zeroed) ----------
__global__ void cvt_xpad_kernel(const float* __restrict__ x, bf16* __restrict__ xp) {
    int idx = blockIdx.x * 256 + threadIdx.x;
    if (idx >= 8 * 2002 * 128) return;
    int c = idx & 127;
    int rest = idx >> 7;
    int tp = rest % 2002;
    int b = rest / 2002;
    float v = 0.f;
    if (tp >= 1 && tp <= 2000) v = x[(b * 2000 + tp - 1) * 128 + c];
    xp[idx] = (bf16)v;
}

// ---------- generic transpose+convert: in fp32 [R][C] -> out [C][Rpad], zero pad r in [R,Rpad) ----------
template <typename OT>
__global__ void transpose_cvt_kernel(const float* __restrict__ in, OT* __restrict__ out,
                                     int R, int C, int Rpad) {
    __shared__ float tile[32][33];
    int tx = threadIdx.x & 31, ty = threadIdx.x >> 5;
    int r0 = blockIdx.y * 32, c0 = blockIdx.x * 32;
    for (int i = ty; i < 32; i += 8) {
        int r = r0 + i, c = c0 + tx;
        tile[i][tx] = (r < R && c < C) ? in[(size_t)r * C + c] : 0.f;
    }
    __syncthreads();
    for (int i = ty; i < 32; i += 8) {
        int c = c0 + i, r = r0 + tx;
        if (c < C && r < Rpad) out[(size_t)c * Rpad + r] = (OT)tile[tx][i];
    }
}

// ---------- zero h1 pad row (t=2000 per batch) ----------
__global__ void zero_aux_kernel(bf16* __restrict__ h1) {
    int idx = blockIdx.x * 256 + threadIdx.x;
    if (idx < 8 * 4096) {
        int b = idx >> 12, n = idx & 4095;
        h1[((size_t)(b * 2001 + 2000)) * 4096 + n] = (bf16)0.f;
    }
}

// ---------- init hseq: buffer 0 = h0 = 0.0f, buffers 1..1024 = sentinel ----------
__global__ void init_hseq_kernel(float* __restrict__ hseq) {
    int idx = blockIdx.x * 1024 + threadIdx.x;
    if (idx < 1025 * 4096) hseq[idx] = (idx < 4096) ? 0.f : SENT;
}

// ---------- unified bf16 MFMA GEMM, 128x128 tile, BK=32, global_load_lds staging ----------
template <int MODE>
__launch_bounds__(256)
__global__ void gemm_kernel(const bf16* __restrict__ A, const bf16* __restrict__ BT,
                            const float* __restrict__ bias, void* __restrict__ Cout) {
    constexpr int KTOT = (MODE == 0) ? 384 : (MODE == 1) ? 12288 : 1024;
    constexpr int MTOT = (MODE == 0) ? 16000 : (MODE == 1) ? 8000 : 8192;
    __shared__ __align__(16) bf16 As[128 * 32];
    __shared__ __align__(16) bf16 Bs[128 * 32];
    const int tid = threadIdx.x;
    const int lane = tid & 63, wave = tid >> 6;
    const int m0 = blockIdx.y * 128, n0 = blockIdx.x * 128;
    const int wm = (wave >> 1) * 64, wn = (wave & 1) * 64;

    f32x4 acc[4][4];
#pragma unroll
    for (int mi = 0; mi < 4; ++mi)
#pragma unroll
        for (int ni = 0; ni < 4; ++ni) acc[mi][ni] = (f32x4){0.f, 0.f, 0.f, 0.f};

    for (int kt = 0; kt < KTOT / 32; ++kt) {
        const int k0 = kt * 32;
        __syncthreads();
#pragma unroll
        for (int s = 0; s < 2; ++s) {
            const int ch = s * 256 + tid;
            const int row = ch >> 2;
            const int ko = (ch & 3) * 8;
            int m = m0 + row;
            if (m > MTOT - 1) m = MTOT - 1;
            const bf16* ga;
            if (MODE == 0) {
                int b = m / 2000, t = m - b * 2000;
                ga = A + ((size_t)(b * 2002 + t + (k0 >> 7)) * 128 + (k0 & 127) + ko);
            } else if (MODE == 1) {
                int b = m / 1000, t = m - b * 1000;
                ga = A + ((size_t)(b * 2001 + 2 * t + (k0 >> 12)) * 4096 + (k0 & 4095) + ko);
            } else {
                ga = A + ((size_t)m * 1024 + k0 + ko);
            }
            const bf16* gb = BT + ((size_t)(n0 + row) * KTOT + k0 + ko);
            const int chbase = s * 256 + wave * 64;
            __builtin_amdgcn_global_load_lds(
                (const __attribute__((address_space(1))) uint32_t*)ga,
                (__attribute__((address_space(3))) uint32_t*)&As[chbase * 8], 16, 0, 0);
            __builtin_amdgcn_global_load_lds(
                (const __attribute__((address_space(1))) uint32_t*)gb,
                (__attribute__((address_space(3))) uint32_t*)&Bs[chbase * 8], 16, 0, 0);
        }
        __syncthreads();
        bf16x8 af[4], bfr[4];
#pragma unroll
        for (int i = 0; i < 4; ++i)
            af[i] = *(const bf16x8*)&As[(wm + i * 16 + (lane & 15)) * 32 + (lane >> 4) * 8];
#pragma unroll
        for (int i = 0; i < 4; ++i)
            bfr[i] = *(const bf16x8*)&Bs[(wn + i * 16 + (lane & 15)) * 32 + (lane >> 4) * 8];
#pragma unroll
        for (int mi = 0; mi < 4; ++mi)
#pragma unroll
            for (int ni = 0; ni < 4; ++ni)
                acc[mi][ni] = __builtin_amdgcn_mfma_f32_16x16x32_bf16(af[mi], bfr[ni], acc[mi][ni], 0, 0, 0);
    }

#pragma unroll
    for (int mi = 0; mi < 4; ++mi) {
        int rb = m0 + wm + mi * 16 + (lane >> 4) * 4;
#pragma unroll
        for (int ni = 0; ni < 4; ++ni) {
            int col = n0 + wn + ni * 16 + (lane & 15);
#pragma unroll
            for (int i = 0; i < 4; ++i) {
                int row = rb + i;
                float v = acc[mi][ni][i];
                if (MODE == 0) {
                    float y = gelu_exact(v + bias[col]);
                    int b = row / 2000, t = row - b * 2000;
                    ((bf16*)Cout)[(size_t)(b * 2001 + t) * 4096 + col] = (bf16)y;
                } else if (MODE == 1) {
                    if (row < 8000) {
                        float y = gelu_exact(v + bias[col]);
                        int b = row / 1000, t = row - b * 1000;
                        ((bf16*)Cout)[(size_t)(b * 1024 + col) * 1024 + t] = (bf16)y;
                    }
                } else {
                    ((float*)Cout)[(size_t)row * 2048 + col] = v + bias[col];
                }
            }
        }
    }
}

// ---------- L2-bypassing (LLC-coherent) accessors: sc0 sc1 on gfx950 ----------
static __device__ __forceinline__ void store_llc_f32(float* p, float v) {
    asm volatile("global_store_dword %0, %1, off sc0 sc1" :: "v"(p), "v"(v) : "memory");
}
static __device__ __forceinline__ float4 load_llc_f4(const void* p) {
    float4 v;
    asm volatile("global_load_dwordx4 %0, %1, off sc0 sc1\n\ts_waitcnt vmcnt(0)"
                 : "=&v"(v) : "v"(p) : "memory");
    return v;
}
static __device__ __forceinline__ bool has_sent(float4 v) {
    return v.x == SENT || v.y == SENT || v.z == SENT || v.w == SENT;
}

// ---------- persistent LSTM: barrier-free sentinel dataflow over hseq[1025][4096] ----------
__launch_bounds__(256, 1)
__global__ void lstm_persistent_kernel(const float* __restrict__ Zin,
                                       const float* __restrict__ WrT,
                                       float* __restrict__ hseq,
                                       float* __restrict__ out) {
    __shared__ __align__(16) float hs[4096];
    const int tid = threadIdx.x, lane = tid & 63, wave = tid >> 6;
    const int j = blockIdx.x * 4 + wave;               // hidden unit 0..511
    float4 w[2][4];
#pragma unroll
    for (int it = 0; it < 2; ++it) {
        const int k = it * 256 + (lane << 2);
#pragma unroll
        for (int g = 0; g < 4; ++g)
            w[it][g] = *(const float4*)&WrT[(size_t)(g * 512 + j) * 512 + k];
    }
    const int b_lane = ((lane & 1) << 2) | (lane & 2) | ((lane >> 2) & 1);
    const float expo = (float)(2 * (j >> 1)) * (1.f / 512.f);
    const float rate = powf(10000.f, -expo);
    float creg = 0.f;

    for (int t = 0; t < 1024; ++t) {
        // Zin gate prefetch (normal cached loads; latency hides under the h-poll)
        const float* zp = Zin + ((size_t)(b_lane * 1024 + t) << 11);
        const float z0 = zp[j], z1 = zp[512 + j], z2 = zp[1024 + j], z3 = zp[1536 + j];

        // poll-load h_t chunks; data is self-validating (sentinel 2.0f = not yet written)
        {
            const char* pA = (const char*)(hseq + ((size_t)t << 12)) + (tid << 4) + 4096;
            const char* pB = pA + 8192;
            float4 h0, h1v, h2v, h3v;
            asm volatile(
                "global_load_dwordx4 %0, %4, off offset:-4096 sc0 sc1\n\t"
                "global_load_dwordx4 %1, %4, off sc0 sc1\n\t"
                "global_load_dwordx4 %2, %5, off offset:-4096 sc0 sc1\n\t"
                "global_load_dwordx4 %3, %5, off sc0 sc1\n\t"
                "s_waitcnt vmcnt(0)"
                : "=&v"(h0), "=&v"(h1v), "=&v"(h2v), "=&v"(h3v)
                : "v"(pA), "v"(pB)
                : "memory");
            while (has_sent(h0)) { __builtin_amdgcn_s_sleep(1); h0 = load_llc_f4(pA - 4096); }
            while (has_sent(h1v)) { __builtin_amdgcn_s_sleep(1); h1v = load_llc_f4(pA); }
            while (has_sent(h2v)) { __builtin_amdgcn_s_sleep(1); h2v = load_llc_f4(pB - 4096); }
            while (has_sent(h3v)) { __builtin_amdgcn_s_sleep(1); h3v = load_llc_f4(pB); }
            *(float4*)&hs[(tid << 2)] = h0;
            *(float4*)&hs[(tid << 2) + 1024] = h1v;
            *(float4*)&hs[(tid << 2) + 2048] = h2v;
            *(float4*)&hs[(tid << 2) + 3072] = h3v;
        }
        __syncthreads();

        float acc[32];
#pragma unroll
        for (int i = 0; i < 32; ++i) acc[i] = 0.f;
#pragma unroll
        for (int it = 0; it < 2; ++it) {
            const int k = it * 256 + (lane << 2);
#pragma unroll
            for (int b = 0; b < 8; ++b) {
                const float4 h4 = *(const float4*)&hs[b * 512 + k];
#pragma unroll
                for (int g = 0; g < 4; ++g) {
                    acc[b * 4 + g] += h4.x * w[it][g].x;
                    acc[b * 4 + g] += h4.y * w[it][g].y;
                    acc[b * 4 + g] += h4.z * w[it][g].z;
                    acc[b * 4 + g] += h4.w * w[it][g].w;
                }
            }
        }
        // exchange-and-specialize butterfly: 32 sums across 64 lanes
#pragma unroll
        for (int s = 0; s < 5; ++s) {
            const int cnt = 16 >> s;
            const bool up = (lane >> s) & 1;
#pragma unroll
            for (int i = 0; i < 16; ++i) {
                if (i < cnt) {
                    float keep = up ? acc[i + cnt] : acc[i];
                    float send = up ? acc[i] : acc[i + cnt];
                    acc[i] = keep + __shfl_xor(send, 1 << s, 64);
                }
            }
        }
        acc[0] += __shfl_xor(acc[0], 32, 64);
        const float zf_o = __shfl(acc[0], lane + 16, 64);
        const float zg_o = __shfl(acc[0], lane + 8, 64);
        const float zo_o = __shfl(acc[0], lane + 24, 64);
        if (lane < 8) {
            const float zi = acc[0] + z0;
            const float zf = zf_o + z1;
            const float zg = zg_o + z2;
            const float zo = zo_o + z3;
            const float ig = 1.f / (1.f + expf(-zi));
            const float fg = 1.f / (1.f + expf(-zf));
            const float og = 1.f / (1.f + expf(-zo));
            creg = fg * creg + ig * tanhf(zg);
            const float h = og * tanhf(creg);
            // publish h_{t+1}: write-through to coherent point; no flag, no fence, no drain
            store_llc_f32(&hseq[((size_t)(t + 1) << 12) + b_lane * 512 + j], h);
            const float ang = (float)t * rate;
            const float pe = (j & 1) ? cosf(ang) : sinf(ang);
            out[((size_t)(b_lane * 1024 + t) << 9) + j] = h + pe;  // normal cached store
        }
        __syncthreads();   // protect hs before next step's staging writes
    }
}

extern "C" void kernel_launch(void* const* d_in, const int* in_sizes, int n_in,
                              void* d_out, int out_size, void* d_ws, size_t ws_size,
                              hipStream_t stream) {
    const float* x  = (const float*)d_in[0];
    const float* w1 = (const float*)d_in[1];
    const float* b1 = (const float*)d_in[2];
    const float* w2 = (const float*)d_in[3];
    const float* b2 = (const float*)d_in[4];
    const float* wk = (const float*)d_in[5];
    const float* wr = (const float*)d_in[6];
    const float* lb = (const float*)d_in[7];
    float* out = (float*)d_out;

    uint8_t* ws = (uint8_t*)d_ws;
    size_t off = 0;
    auto alloc = [&](size_t bytes) {
        void* p = ws + off;
        off += (bytes + 255) & ~(size_t)255;
        return p;
    };
    bf16* xpad = (bf16*)alloc((size_t)8 * 2002 * 128 * 2);
    bf16* W1T  = (bf16*)alloc((size_t)4096 * 384 * 2);
    bf16* W2T  = (bf16*)alloc((size_t)1024 * 12288 * 2);
    bf16* WkT  = (bf16*)alloc((size_t)2048 * 1024 * 2);
    float* WrT = (float*)alloc((size_t)2048 * 512 * 4);
    bf16* h1   = (bf16*)alloc((size_t)8 * 2001 * 4096 * 2);   // Zin aliases this after conv2
    bf16* h2T  = (bf16*)alloc((size_t)8 * 1024 * 1024 * 2);
    float* hseq = (float*)alloc((size_t)1025 * 4096 * 4);     // per-step h buffers + sentinels
    float* Zin = (float*)h1;

    cvt_xpad_kernel<<<(8 * 2002 * 128 + 255) / 256, 256, 0, stream>>>(x, xpad);
    transpose_cvt_kernel<bf16><<<dim3(128, 12), 256, 0, stream>>>(w1, W1T, 384, 4096, 384);
    transpose_cvt_kernel<bf16><<<dim3(32, 384), 256, 0, stream>>>(w2, W2T, 12288, 1024, 12288);
    transpose_cvt_kernel<bf16><<<dim3(64, 32), 256, 0, stream>>>(wk, WkT, 1000, 2048, 1024);
    transpose_cvt_kernel<float><<<dim3(64, 16), 256, 0, stream>>>(wr, WrT, 512, 2048, 512);
    zero_aux_kernel<<<(8 * 4096 + 255) / 256, 256, 0, stream>>>(h1);
    init_hseq_kernel<<<(1025 * 4096 + 1023) / 1024, 1024, 0, stream>>>(hseq);

    gemm_kernel<0><<<dim3(32, 125), 256, 0, stream>>>(xpad, W1T, b1, (void*)h1);
    gemm_kernel<1><<<dim3(8, 63), 256, 0, stream>>>(h1, W2T, b2, (void*)h2T);
    gemm_kernel<2><<<dim3(16, 64), 256, 0, stream>>>(h2T, WkT, lb, (void*)Zin);

    lstm_persistent_kernel<<<NWG, 256, 0, stream>>>(Zin, WrT, hseq, out);
}